// Round 6
// baseline (426.097 us; speedup 1.0000x reference)
//
#include <hip/hip_runtime.h>
#include <hip/hip_bf16.h>

// B=8, N=4096, D=1024, 3 iterations.
// r11: latency-tuning of r10's proven 16-launch structure. Calibration from
// r5->r10: launch overhead ~1us => the ~345us (ex-fill) is kernel-resident
// time, dominated by deep serial scalar loops on tiny grids. Fixes:
//  - ksu: stats + bst-update + softmax fused IN REGISTERS (one pass, no bst
//    round-trip; kout loses its softmax blocks)
//  - float4 vectorization of all staging/zero loops (kv/kout/kt/kdet/stats)
//  - kfd: 1024 blocks (8 rows/wave) -> 4 blocks/CU for latency hiding
//  - kprep: vectorized M-mean; q0 GEMV via LDS-staged coalesced Wh rows
// Algebra (r5): t = qc@M ; v = t@Wf^T ; delta[b,n] = feat[b,n,:].v
//               s = c@feat ; u = s@Wf ; out = u@M^T
// r8/r9 lesson: grid sync ~55us/sync on MI355X — persistent kernels dead end.
// r6/r7 lesson: Q=Wf@M^T precompute is a bad trade.
// Harness poisons a 512 MiB workspace (~77 us/call, fillBufferAligned).

using u16 = unsigned short;
using u32 = unsigned int;
using u8  = unsigned char;
using u64 = unsigned long long;

#define SELU_L 1.0507009873554805f
#define SELU_A 1.6732632423543772f

__device__ __align__(16) float g_M[1048576];   // Wg mean (fp32), [d][j]
__device__ __align__(16) float g_q[8192];      // q0 (zeroed kdet, filled kprep)
__device__ __align__(16) float g_qc[8192];     // persisted post-LN q state
__device__ __align__(16) float g_t[8192];      // t = qc @ M
__device__ __align__(16) float g_u[8192];      // u = s @ Wf
__device__ __align__(16) float g_s[8192];      // s = c @ feat
__device__ __align__(16) float g_bst[32768];   // b logits state
__device__ __align__(16) float g_c[32768];     // softmax
__device__ __align__(16) float g_delta[32768];
__device__ __align__(16) float g_outv[8192];   // out of iters 0,1
__device__ __align__(16) float g_outv2[8192];  // out of iter 2
__device__ __align__(16) float g_v[8192];
__device__ int g_dt[12];        // 0..8: 0=bf16,1=f32 per float input; [9]=mask

__device__ __forceinline__ float blo(u32 u){ return __uint_as_float(u << 16); }
__device__ __forceinline__ float bhi(u32 u){ return __uint_as_float(u & 0xffff0000u); }
__device__ __forceinline__ float b2f(u16 u){ return __uint_as_float(((u32)u) << 16); }

__device__ __forceinline__ void unpack8(uint4 x, float* f){
  f[0]=blo(x.x); f[1]=bhi(x.x); f[2]=blo(x.y); f[3]=bhi(x.y);
  f[4]=blo(x.z); f[5]=bhi(x.z); f[6]=blo(x.w); f[7]=bhi(x.w);
}

__device__ __forceinline__ float ldf(const void* p, size_t i, int dt){
  return dt ? ((const float*)p)[i] : b2f(((const u16*)p)[i]);
}
__device__ __forceinline__ void load8(const void* base, size_t idx, int dt, float* f){
  if (dt == 0) {
    uint4 x = *(const uint4*)((const u16*)base + idx);
    unpack8(x, f);
  } else {
    const float* p = (const float*)base + idx;
    float4 a = *(const float4*)p, b = *(const float4*)(p + 4);
    f[0]=a.x; f[1]=a.y; f[2]=a.z; f[3]=a.w; f[4]=b.x; f[5]=b.y; f[6]=b.z; f[7]=b.w;
  }
}

__device__ __forceinline__ float wredsum(float x){
#pragma unroll
  for (int o = 32; o; o >>= 1) x += __shfl_xor(x, o, 64);
  return x;
}

__device__ __forceinline__ bool mon(const u8* maskp, int e, int mode){
  if (mode == 0) return maskp[e] != 0;
  if (mode == 1) return ((const int*)maskp)[e] != 0;
  if (mode == 2 || mode == 4) return ((const u16*)maskp)[e] != 0;
  if (mode == 3) return ((const u32*)maskp)[e] != 0;
  return ((const u64*)maskp)[e] != 0ULL;
}

// ---- dtype sniffer (wave-parallel) + zero q,t,u,s (float4) ------------------
__global__ void kdet(const void* p0, const void* p1, const void* p2, const void* p3,
                     const void* p4, const void* p5, const void* p6, const void* p7,
                     const void* p8, const void* p9)
{
  const void* ps[10] = {p0,p1,p2,p3,p4,p5,p6,p7,p8,p9};
  int tid = threadIdx.x;
  int w = tid >> 6, lane = tid & 63;
  if (w < 9) {
    const u16* wp = (const u16*)ps[w];
    u16 x0 = wp[lane], x1 = wp[64 + lane];
    int e0 = (x0 >> 7) & 0xFF, e1 = (x1 >> 7) & 0xFF;
    u64 nz0 = __ballot(x0 != 0), nz1 = __ballot(x1 != 0);
    u64 pa0 = __ballot(x0 != 0 && e0 >= 0x70 && e0 <= 0x8F);
    u64 pa1 = __ballot(x1 != 0 && e1 >= 0x70 && e1 <= 0x8F);
    if (lane == 0) {
      const u64 evenm = 0x5555555555555555ULL;
      int nz = __popcll(nz0) + __popcll(nz1);
      int pass = __popcll(pa0) + __popcll(pa1);
      int evenNZ = __popcll(nz0 & evenm) + __popcll(nz1 & evenm);
      int oddNZ  = nz - evenNZ;
      int dt;
      if (nz == 0)                    dt = 0;
      else if (evenNZ == 0 && oddNZ)  dt = 1;    // f32 signature
      else                            dt = (pass * 10 >= nz * 9) ? 0 : 1;
      g_dt[w] = dt;
    }
  } else if (w == 9) {
    const u8* mp = (const u8*)ps[9];
    u64 v = ((const u64*)mp)[lane];
    bool f16c=false, isF=false, nz01=false, nzNon4=false, nzM8_4=false, anynz=false;
#pragma unroll
    for (int j = 0; j < 8; ++j) {
      u8 cb = (u8)(v >> (8 * j));
      if (!cb) continue;
      int i = lane * 8 + j;
      anynz = true;
      if (cb == 0x3C && (i & 1)) f16c = true;
      if (cb == 0x3F || cb == 0x80) isF = true;
      int m = i & 3;
      if (m == 0 || m == 1) nz01 = true;
      if (m != 0) nzNon4 = true;
      if ((i & 7) == 4) nzM8_4 = true;
    }
    bool A  = __ballot(f16c)   != 0;
    bool Bf = __ballot(isF)    != 0;
    bool C  = __ballot(nz01)   != 0;
    bool Dn = __ballot(nzNon4) != 0;
    bool E  = __ballot(nzM8_4) != 0;
    bool F  = __ballot(anynz)  != 0;
    if (lane == 0) {
      int mode;
      if (A)       mode = 4;
      else if (Bf) mode = C ? 2 : 3;
      else if (Dn) mode = 0;
      else if (E)  mode = 1;
      else if (F)  mode = 5;
      else         mode = 1;
      g_dt[9] = mode;
    }
  }
  float4 z = make_float4(0.f, 0.f, 0.f, 0.f);
  for (int i = tid; i < 2048; i += 640) {
    ((float4*)g_q)[i] = z; ((float4*)g_t)[i] = z;
    ((float4*)g_u)[i] = z; ((float4*)g_s)[i] = z;
  }
}

// ---- prep: M vec (<512) | q0 LDS-staged (<576) | bst (<608) | c0 (<616) -----
__global__ void __launch_bounds__(256)
kprep(const void* __restrict__ Wg, const void* __restrict__ Wh,
      const void* __restrict__ query, const u8* __restrict__ maskp)
{
  __shared__ float wl[8192];                     // 32 KB Wh tile (q0 branch)
  __shared__ float ql[512];
  int blk = blockIdx.x, tid = threadIdx.x;
  if (blk < 512) {
    int dtg = g_dt[4];
    int e = blk * 2048 + tid * 8;
    float a[8] = {0,0,0,0,0,0,0,0};
#pragma unroll
    for (int g = 0; g < 4; ++g) {
      float f[8];
      load8(Wg, (size_t)g * 1048576 + e, dtg, f);
#pragma unroll
      for (int u = 0; u < 8; ++u) a[u] += f[u];
    }
    *(float4*)(g_M + e)     = make_float4(a[0]*0.25f, a[1]*0.25f, a[2]*0.25f, a[3]*0.25f);
    *(float4*)(g_M + e + 4) = make_float4(a[4]*0.25f, a[5]*0.25f, a[6]*0.25f, a[7]*0.25f);
  } else if (blk < 576) {
    // q0[b,k] += sum_{d in 64-chunk} query[b,d]*Wh[d,k]; Wh staged via LDS rows
    int dtq = g_dt[0], dth = g_dt[2];
    int blk2 = blk - 512;
    int kt4 = blk2 & 3, dc = blk2 >> 2;          // k-tile 256, d-chunk 64
    for (int idx = tid; idx < 512; idx += 256) {
      int b = idx >> 6, dl = idx & 63;
      ql[idx] = ldf(query, b * 1024 + dc * 64 + dl, dtq);
    }
    float acc[8] = {0,0,0,0,0,0,0,0};
    int cq = tid & 31, r4 = tid >> 5;            // col chunk (x8), row group
#pragma unroll
    for (int h = 0; h < 2; ++h) {                // two 32-row halves
      if (h) __syncthreads();
#pragma unroll
      for (int u4 = 0; u4 < 4; ++u4) {
        int r = r4 * 4 + u4;                     // 0..31
        float f[8];
        load8(Wh, (size_t)(dc * 64 + h * 32 + r) * 1024 + kt4 * 256 + cq * 8, dth, f);
#pragma unroll
        for (int u = 0; u < 8; ++u) wl[r * 256 + cq * 8 + u] = f[u];
      }
      __syncthreads();
      for (int dd = 0; dd < 32; ++dd) {
        float w = wl[dd * 256 + tid];
        int dl = h * 32 + dd;
#pragma unroll
        for (int b = 0; b < 8; ++b) acc[b] += ql[(b << 6) + dl] * w;
      }
    }
    int k = kt4 * 256 + tid;
#pragma unroll
    for (int b = 0; b < 8; ++b) atomicAdd(&g_q[b * 1024 + k], acc[b]);
  } else if (blk < 608) {
    int mode = g_dt[9];
    int e0 = (blk - 576) * 1024 + tid * 4;
#pragma unroll
    for (int j = 0; j < 4; ++j) {
      int e = e0 + j;
      g_bst[e] = mon(maskp, e, mode) ? -1e18f : 0.f;
    }
  } else {
    // c0 directly from mask: softmax of 0/-1e18 row == uniform over unmasked
    __shared__ int sc[256];
    int mode = g_dt[9];
    int b = blk - 608;
    u32 bits = 0; int cnt = 0;
#pragma unroll
    for (int r = 0; r < 16; ++r) {
      int n = tid + 256 * r;
      bool on = mon(maskp, b * 4096 + n, mode);
      if (on) bits |= (1u << r); else ++cnt;
    }
    sc[tid] = cnt; __syncthreads();
    for (int s2 = 128; s2; s2 >>= 1) { if (tid < s2) sc[tid] += sc[tid + s2]; __syncthreads(); }
    int ct = sc[0];
    float inv = 1.f / (float)(ct ? ct : 4096);
    float moff = ct ? 0.f : inv;
#pragma unroll
    for (int r = 0; r < 16; ++r) {
      int n = tid + 256 * r;
      g_c[b * 4096 + n] = ((bits >> r) & 1u) ? moff : inv;
    }
  }
}

// ---- redundant q-update into LDS: ql = LN(qsrc + selu(osrc*scale)) ----------
__device__ __forceinline__ void build_ql(float* ql, const float* qsrc,
                                         const float* osrc, float scale,
                                         const void* lnw, const void* lnb, int tid)
{
  int w = tid >> 6, lane = tid & 63;
  int dtw = g_dt[5], dtb = g_dt[6];
#pragma unroll
  for (int rr = 0; rr < 2; ++rr) {
    int b = w + rr * 4;
    const float* qb = qsrc + b * 1024;
    const float* ob = osrc + b * 1024;
    float x[16]; float sum = 0.f, sq = 0.f;
#pragma unroll
    for (int cc = 0; cc < 4; ++cc) {
      float4 qv = *(const float4*)(qb + cc * 256 + lane * 4);
      float4 ov = *(const float4*)(ob + cc * 256 + lane * 4);
      float q4[4] = {qv.x, qv.y, qv.z, qv.w};
      float o4[4] = {ov.x, ov.y, ov.z, ov.w};
#pragma unroll
      for (int e = 0; e < 4; ++e) {
        float o = o4[e] * scale;
        float se = (o > 0.f) ? SELU_L * o : SELU_L * SELU_A * expm1f(o);
        float val = q4[e] + se;
        x[cc * 4 + e] = val; sum += val; sq += val * val;
      }
    }
    sum = wredsum(sum); sq = wredsum(sq);
    float mean = sum * (1.f / 1024.f);
    float var = fmaxf(sq * (1.f / 1024.f) - mean * mean, 0.f);   // ddof=0
    float rstd = rsqrtf(var + 1e-5f);
#pragma unroll
    for (int cc = 0; cc < 4; ++cc)
#pragma unroll
      for (int e = 0; e < 4; ++e) {
        int d = cc * 256 + lane * 4 + e;
        ql[b * 1024 + d] = (x[cc * 4 + e] - mean) * rstd * ldf(lnw, d, dtw)
                           + ldf(lnb, d, dtb);
      }
  }
  __syncthreads();
}

// ---- kt: {LN -> ql} + t = ql@M (blk<256) | zero u (256..263) ----------------
__global__ void __launch_bounds__(256)
kt(const void* __restrict__ lnw, const void* __restrict__ lnb, int phase)
{
  __shared__ __align__(16) float ql[8192];
  int blk = blockIdx.x, tid = threadIdx.x;
  if (blk >= 256) {
    int b = blk - 256;
    *(float4*)(g_u + b * 1024 + tid * 4) = make_float4(0.f, 0.f, 0.f, 0.f);
    return;
  }
  if (phase == 0) {
    for (int it = tid; it < 2048; it += 256)
      ((float4*)ql)[it] = ((const float4*)g_q)[it];
    __syncthreads();
  } else {
    build_ql(ql, g_qc, g_outv, 1.f / 4096.f, lnw, lnb, tid);
  }
  if (blk == 0) {                                // persist qc for next LN
    for (int it = tid; it < 2048; it += 256)
      ((float4*)g_qc)[it] = ((const float4*)ql)[it];
  }
  int jt = blk & 3, dc4 = blk >> 2;
  int j = jt * 256 + tid;
  float acc[8] = {0,0,0,0,0,0,0,0};
  for (int dd = 0; dd < 16; ++dd) {
    int d = dc4 * 16 + dd;
    float mv = g_M[(size_t)d * 1024 + j];
#pragma unroll
    for (int b = 0; b < 8; ++b) acc[b] += ql[(b << 10) + d] * mv;
  }
#pragma unroll
  for (int b = 0; b < 8; ++b) atomicAdd(&g_t[b * 1024 + j], acc[b]);
}

// ---- kv: v[b,k] = t[b,:] . Wf[k,:]  (256 blocks, wave per k row) ------------
__global__ void __launch_bounds__(256) kv(const void* __restrict__ Wf)
{
  __shared__ __align__(16) float shm[8192];
  int tid = threadIdx.x;
  int dtf = g_dt[3];
  for (int it = tid; it < 2048; it += 256)
    ((float4*)shm)[it] = ((const float4*)g_t)[it];
  __syncthreads();
  int w = tid >> 6, lane = tid & 63;
  int k = blockIdx.x * 4 + w;
  size_t row = (size_t)k * 1024;
  float f[16];
  load8(Wf, row + lane * 8, dtf, f);
  load8(Wf, row + 512 + lane * 8, dtf, f + 8);
  float acc[8];
#pragma unroll
  for (int b = 0; b < 8; ++b) {
    const float* tb = shm + b * 1024;
    float d = 0.f;
#pragma unroll
    for (int j = 0; j < 8; ++j) d += f[j]     * tb[lane * 8 + j];
#pragma unroll
    for (int j = 0; j < 8; ++j) d += f[8 + j] * tb[512 + lane * 8 + j];
    acc[b] = wredsum(d);
  }
  if (lane == 0) {
#pragma unroll
    for (int b = 0; b < 8; ++b) g_v[b * 1024 + k] = acc[b];
  }
}

// ---- kfd: feat pass, 1024 blocks x 32 rows (blk<1024) | zero u (1024..) -----
__global__ void __launch_bounds__(256)
kfd(const void* __restrict__ feat, int need_delta)
{
  __shared__ float sl[4][1024];
  int blkx = blockIdx.x, tid = threadIdx.x;
  if (blkx >= 1024) {
    int b = blkx - 1024;
    *(float4*)(g_u + b * 1024 + tid * 4) = make_float4(0.f, 0.f, 0.f, 0.f);
    return;
  }
  int w = tid >> 6, lane = tid & 63;
  int b = blkx >> 7, ch = blkx & 127;
  int dtf = g_dt[1];
  float vr[16];
#pragma unroll
  for (int j = 0; j < 16; ++j) vr[j] = 0.f;
  if (need_delta) {
    const float* vb = g_v + b * 1024;
    float4 v0 = *(const float4*)(vb + lane * 8);
    float4 v1 = *(const float4*)(vb + lane * 8 + 4);
    float4 v2 = *(const float4*)(vb + 512 + lane * 8);
    float4 v3 = *(const float4*)(vb + 512 + lane * 8 + 4);
    vr[0]=v0.x; vr[1]=v0.y; vr[2]=v0.z; vr[3]=v0.w;
    vr[4]=v1.x; vr[5]=v1.y; vr[6]=v1.z; vr[7]=v1.w;
    vr[8]=v2.x; vr[9]=v2.y; vr[10]=v2.z; vr[11]=v2.w;
    vr[12]=v3.x; vr[13]=v3.y; vr[14]=v3.z; vr[15]=v3.w;
  }
  int n0 = ch * 32 + w * 8;
  float4 c0 = *(const float4*)(g_c + b * 4096 + n0);
  float4 c1 = *(const float4*)(g_c + b * 4096 + n0 + 4);
  float cc[8] = {c0.x, c0.y, c0.z, c0.w, c1.x, c1.y, c1.z, c1.w};
  float acc[16];
#pragma unroll
  for (int j = 0; j < 16; ++j) acc[j] = 0.f;
  for (int r = 0; r < 8; ++r) {
    int n = n0 + r;
    size_t row = ((size_t)b * 4096 + n) * 1024;
    float f[16];
    load8(feat, row + lane * 8, dtf, f);
    load8(feat, row + 512 + lane * 8, dtf, f + 8);
    float cn = cc[r];
#pragma unroll
    for (int j = 0; j < 16; ++j) acc[j] += cn * f[j];
    if (need_delta) {
      float dot = 0.f;
#pragma unroll
      for (int j = 0; j < 16; ++j) dot += f[j] * vr[j];
      dot = wredsum(dot);
      if (lane == 0) g_delta[b * 4096 + n] = dot;
    }
  }
#pragma unroll
  for (int j = 0; j < 8; ++j) {
    sl[w][lane * 8 + j] = acc[j];
    sl[w][512 + lane * 8 + j] = acc[8 + j];
  }
  __syncthreads();
#pragma unroll
  for (int j = 0; j < 4; ++j) {
    int k = tid * 4 + j;
    float val = sl[0][k] + sl[1][k] + sl[2][k] + sl[3][k];
    atomicAdd(&g_s[b * 1024 + k], val);
  }
}

// ---- ksu: fused stats+bst+softmax in regs (blk<8) | u = s@Wf (8..263) -------
__global__ void __launch_bounds__(256)
ksu(const void* __restrict__ Wf, int do_stats)
{
  __shared__ float sm[256];
  int blk = blockIdx.x, tid = threadIdx.x;
  if (blk < 8) {
    if (!do_stats) return;
    int b = blk;
    const float* drow = g_delta + b * 4096;
    float xs[16];
    float sum = 0.f, sq = 0.f;
#pragma unroll
    for (int rr = 0; rr < 4; ++rr) {
      float4 x4 = *(const float4*)(drow + tid * 4 + rr * 1024);
      float xx[4] = {x4.x, x4.y, x4.z, x4.w};
#pragma unroll
      for (int j = 0; j < 4; ++j) { xs[rr*4+j] = xx[j]; sum += xx[j]; sq += xx[j]*xx[j]; }
    }
    sm[tid] = sum; __syncthreads();
    for (int s2 = 128; s2; s2 >>= 1) { if (tid < s2) sm[tid] += sm[tid + s2]; __syncthreads(); }
    sum = sm[0]; __syncthreads();
    sm[tid] = sq; __syncthreads();
    for (int s2 = 128; s2; s2 >>= 1) { if (tid < s2) sm[tid] += sm[tid + s2]; __syncthreads(); }
    sq = sm[0]; __syncthreads();
    float mean = sum / 4096.f;
    float var = fmaxf((sq - 4096.f * mean * mean) / 4095.f, 0.f);  // ddof=1
    float inv = 1.f / (sqrtf(var) + 1e-9f);
    // bst update in-reg + writeback; track max for softmax
    float* brow = g_bst + b * 4096;
    float mx = -3.4e38f;
#pragma unroll
    for (int rr = 0; rr < 4; ++rr) {
      float4 b4 = *(const float4*)(brow + tid * 4 + rr * 1024);
      float bb[4] = {b4.x, b4.y, b4.z, b4.w};
#pragma unroll
      for (int j = 0; j < 4; ++j) {
        float nb = bb[j] + (xs[rr*4+j] - mean) * inv;
        xs[rr*4+j] = nb;
        mx = fmaxf(mx, nb);
      }
      *(float4*)(brow + tid * 4 + rr * 1024) =
          make_float4(xs[rr*4], xs[rr*4+1], xs[rr*4+2], xs[rr*4+3]);
    }
    sm[tid] = mx; __syncthreads();
    for (int s2 = 128; s2; s2 >>= 1) { if (tid < s2) sm[tid] = fmaxf(sm[tid], sm[tid + s2]); __syncthreads(); }
    mx = sm[0]; __syncthreads();
    float es = 0.f;
#pragma unroll
    for (int k16 = 0; k16 < 16; ++k16) { float e = __expf(xs[k16] - mx); xs[k16] = e; es += e; }
    sm[tid] = es; __syncthreads();
    for (int s2 = 128; s2; s2 >>= 1) { if (tid < s2) sm[tid] += sm[tid + s2]; __syncthreads(); }
    float cinv = 1.f / sm[0];
    float* crow = g_c + b * 4096;
#pragma unroll
    for (int rr = 0; rr < 4; ++rr)
      *(float4*)(crow + tid * 4 + rr * 1024) =
          make_float4(xs[rr*4]*cinv, xs[rr*4+1]*cinv, xs[rr*4+2]*cinv, xs[rr*4+3]*cinv);
    return;
  }
  int dtf = g_dt[3];
  int blk2 = blk - 8;
  int jt = blk2 & 3, kc4 = blk2 >> 2;
  if (tid < 128) {
    int b = tid >> 4, kk = tid & 15;
    sm[tid] = g_s[b * 1024 + kc4 * 16 + kk];
  }
  __syncthreads();
  int j = jt * 256 + tid;
  float acc[8] = {0,0,0,0,0,0,0,0};
  for (int kk = 0; kk < 16; ++kk) {
    int k = kc4 * 16 + kk;
    float w = ldf(Wf, (size_t)k * 1024 + j, dtf);
#pragma unroll
    for (int b = 0; b < 8; ++b) acc[b] += sm[(b << 4) + kk] * w;
  }
#pragma unroll
  for (int b = 0; b < 8; ++b) atomicAdd(&g_u[b * 1024 + j], acc[b]);
}

// ---- kout: out = u@M^T (blk<256) | zero t (256..263) | zero s (264..271) ----
__global__ void __launch_bounds__(256) kout(int dst2)
{
  __shared__ __align__(16) float sh[8192];
  int blk = blockIdx.x, tid = threadIdx.x;
  if (blk >= 256) {
    if (blk < 264) {
      int b = blk - 256;
      *(float4*)(g_t + b * 1024 + tid * 4) = make_float4(0.f, 0.f, 0.f, 0.f);
    } else {
      int b = blk - 264;
      *(float4*)(g_s + b * 1024 + tid * 4) = make_float4(0.f, 0.f, 0.f, 0.f);
    }
    return;
  }
  float* dst = dst2 ? g_outv2 : g_outv;
  for (int it = tid; it < 2048; it += 256)
    ((float4*)sh)[it] = ((const float4*)g_u)[it];
  __syncthreads();
  int w = tid >> 6, lane = tid & 63;
  int d = blk * 4 + w;
  const float* row = g_M + (size_t)d * 1024;
  float f[16];
#pragma unroll
  for (int cc = 0; cc < 4; ++cc) {
    float4 x = *(const float4*)(row + cc * 256 + lane * 4);
    f[cc*4+0]=x.x; f[cc*4+1]=x.y; f[cc*4+2]=x.z; f[cc*4+3]=x.w;
  }
  float acc[8];
#pragma unroll
  for (int b = 0; b < 8; ++b) {
    const float* ub = sh + b * 1024;
    float dd = 0.f;
#pragma unroll
    for (int cc = 0; cc < 4; ++cc)
#pragma unroll
      for (int e = 0; e < 4; ++e) dd += f[cc * 4 + e] * ub[cc * 256 + lane * 4 + e];
    acc[b] = wredsum(dd);
  }
  if (lane == 0) {
#pragma unroll
    for (int b = 0; b < 8; ++b) dst[b * 1024 + d] = acc[b];
  }
}

// ---- kfin: double LN (outv then outv2) + q3@Wout^T + bout -------------------
__global__ void __launch_bounds__(256)
kfin(const void* __restrict__ Wout, const void* __restrict__ bout,
     const void* __restrict__ lnw, const void* __restrict__ lnb,
     float* __restrict__ out)
{
  __shared__ __align__(16) float ql[8192];
  int tid = threadIdx.x;
  build_ql(ql, g_qc, g_outv, 1.f / 4096.f, lnw, lnb, tid);   // qc2
  build_ql(ql, ql, g_outv2, 1.f, lnw, lnb, tid);             // qc3
  int w = tid >> 6, lane = tid & 63;
  int o = blockIdx.x * 4 + w;
  int dto = g_dt[7], dtb = g_dt[8];
  size_t row = (size_t)o * 1024;
  float f[16];
  load8(Wout, row + lane * 8, dto, f);
  load8(Wout, row + 512 + lane * 8, dto, f + 8);
  float acc[8];
#pragma unroll
  for (int b = 0; b < 8; ++b) {
    const float* qb = ql + b * 1024;
    float d = 0.f;
#pragma unroll
    for (int j = 0; j < 8; ++j) d += f[j]     * qb[lane * 8 + j];
#pragma unroll
    for (int j = 0; j < 8; ++j) d += f[8 + j] * qb[512 + lane * 8 + j];
    acc[b] = wredsum(d);
  }
  if (lane == 0) {
    float bo = ldf(bout, o, dtb);
#pragma unroll
    for (int b = 0; b < 8; ++b) out[b * 1024 + o] = acc[b] + bo;
  }
}

extern "C" void kernel_launch(void* const* d_in, const int* in_sizes, int n_in,
                              void* d_out, int out_size, void* d_ws, size_t ws_size,
                              hipStream_t stream)
{
  const void* query = d_in[0];
  const void* feat  = d_in[1];
  const void* Wh    = d_in[2];
  const void* Wf    = d_in[3];
  const void* Wg    = d_in[4];
  const void* lnw   = d_in[5];
  const void* lnb   = d_in[6];
  const void* Wout  = d_in[7];
  const void* bout  = d_in[8];
  const u8*   maskp = (const u8*)d_in[9];
  (void)in_sizes; (void)n_in; (void)out_size; (void)d_ws; (void)ws_size;

  kdet<<<1, 640, 0, stream>>>(query, feat, Wh, Wf, Wg, lnw, lnb, Wout, bout, maskp);
  kprep<<<616, 256, 0, stream>>>(Wg, Wh, query, maskp);

  // iter 0
  kt<<<264, 256, 0, stream>>>(lnw, lnb, 0);      // q0 copy + t ; zero u
  kv<<<256, 256, 0, stream>>>(Wf);
  kfd<<<1024, 256, 0, stream>>>(feat, 1);
  ksu<<<264, 256, 0, stream>>>(Wf, 1);           // stats+softmax1 ; u
  kout<<<272, 256, 0, stream>>>(0);              // out0 ; zero t,s
  // iter 1
  kt<<<264, 256, 0, stream>>>(lnw, lnb, 1);      // LN1 + t ; zero u
  kv<<<256, 256, 0, stream>>>(Wf);
  kfd<<<1024, 256, 0, stream>>>(feat, 1);
  ksu<<<264, 256, 0, stream>>>(Wf, 1);           // stats+softmax2 ; u
  kout<<<272, 256, 0, stream>>>(0);              // out1 ; zero t,s
  // iter 2 (last: no t/v/delta; out -> g_outv2)
  kfd<<<1032, 256, 0, stream>>>(feat, 0);        // s only ; zero u
  ksu<<<264, 256, 0, stream>>>(Wf, 0);           // u only
  kout<<<256, 256, 0, stream>>>(1);              // out2 -> g_outv2
  kfin<<<256, 256, 0, stream>>>(Wout, bout, lnw, lnb, (float*)d_out);
}